// Round 15
// baseline (690.613 us; speedup 1.0000x reference)
//
#include <hip/hip_runtime.h>
#include <hip/hip_bf16.h>
#include <math.h>

// ---- problem constants ----
#define S_    2048
#define NC_   7
#define MAXK  819
#define NK    1024          // a_cat/Vcat row stride per z
#define KP    896           // trimmed valid top-k rows (7*128)
#define Z_    14            // B*NUM_CATS
#define NEGV  (-10000.0f)

typedef __attribute__((ext_vector_type(8))) short bf16x8;
typedef __attribute__((ext_vector_type(4))) float f32x4;

#define CFENCE asm volatile("" ::: "memory")
#define BAR    do { CFENCE; __builtin_amdgcn_s_barrier(); CFENCE; } while (0)

__device__ __forceinline__ void gload_lds16(const void* g, void* l) {
  __builtin_amdgcn_global_load_lds((const __attribute__((address_space(1))) unsigned int*)g,
                                   (__attribute__((address_space(3))) unsigned int*)l, 16, 0, 0);
}

__device__ __forceinline__ float gelu_exact(float x) {
  return 0.5f * x * (1.0f + erff(x * 0.70710678118654752f));
}
__device__ __forceinline__ unsigned short f2bf(float x) {
  __hip_bfloat16 h = __float2bfloat16(x);
  return *(unsigned short*)&h;
}
__device__ __forceinline__ float bf2f(unsigned short u) {
  __hip_bfloat16 h; *(unsigned short*)&h = u;
  return __bfloat162float(h);
}
__device__ __forceinline__ unsigned fkey(float f) {
  unsigned u = __float_as_uint(f);
  return (u & 0x80000000u) ? ~u : (u | 0x80000000u);
}

// ============ 256x256 8-wave GEMM, BK=64, deep pipeline (r10-proven schedule) ============
template<bool OBF16, int EPI, bool FCM>
__global__ __launch_bounds__(512, 2) void k_gemm8(
    const __hip_bfloat16* __restrict__ A, const __hip_bfloat16* __restrict__ A2,
    const __hip_bfloat16* __restrict__ B,
    void* __restrict__ Cv, const float* __restrict__ bias1, const float* __restrict__ bias2,
    const float* __restrict__ tkv, const int* __restrict__ kvp,
    int K, int nbn, long strideA, long strideB, int bmod7, long strideC,
    int ldc, int Mstore, int Nstore, int Msplit)
{
  __shared__ __align__(16) char lds[2][65536];   // per buf: A[0,32K) B[32K,64K)
  const int tid = threadIdx.x;
  const int z = blockIdx.z;
  const int nwg = gridDim.x;
  const int xcd = blockIdx.x & 7, loc = blockIdx.x >> 3;
  const int q = nwg >> 3, rr = nwg & 7;
  const int wg = (xcd < rr ? xcd * (q + 1) : rr * (q + 1) + (xcd - rr) * q) + loc;
  const int bm = wg / nbn, bn = wg % nbn;
  const int m0 = bm * 256, n0 = bn * 256;
  const bool set1 = FCM && (m0 >= Msplit);
  const __hip_bfloat16* pA = FCM ? (set1 ? (A2 - (long)Msplit * K) : A)
                                 : (A + (long)z * strideA);
  const __hip_bfloat16* pB = FCM ? (B + (set1 ? strideB : 0))
                                 : (B + (long)(bmod7 ? (z % 7) : z) * strideB);
  const int wave = tid >> 6, lane = tid & 63;
  const int wm = wave >> 2, wn = wave & 3;
  const int lr = lane & 15, kh = lane >> 4;
  const long Kb = (long)K * 2;

  f32x4 acc[8][4];
  #pragma unroll
  for (int i = 0; i < 8; ++i)
    #pragma unroll
    for (int j = 0; j < 4; ++j)
      #pragma unroll
      for (int r4 = 0; r4 < 4; ++r4) acc[i][j][r4] = 0.0f;

  auto stageHalf = [&](int bb, int isB, int rh, int kt) {
    const long kbyte = (long)kt * 128;
    const char* basep = isB ? (const char*)pB + (long)(n0 + rh * 128) * Kb
                            : (const char*)pA + (long)(m0 + rh * 128) * Kb;
    #pragma unroll
    for (int j = 0; j < 2; ++j) {
      int off = j * 8192 + tid * 16;
      int row = off >> 7, col = off & 127;
      int gc = col ^ (((rh * 128 + row) & 7) << 4);
      gload_lds16(basep + (long)row * Kb + kbyte + gc,
                  &lds[bb][isB * 32768 + (rh * 128 + row) * 128 + col]);
    }
  };
  auto readA = [&](int c, int g, int kk) -> bf16x8 {
    int row = wm * 128 + g * 16 + lr;
    int colb = kk * 64 + kh * 16;
    return *(const bf16x8*)&lds[c][row * 128 + (colb ^ ((row & 7) << 4))];
  };
  auto readB = [&](int c, int ni, int kk) -> bf16x8 {
    int row = wn * 64 + ni * 16 + lr;
    int colb = kk * 64 + kh * 16;
    return *(const bf16x8*)&lds[c][32768 + row * 128 + (colb ^ ((row & 7) << 4))];
  };
  auto mfma4 = [&](int g0, bf16x8* af, bf16x8* bfr) {
    __builtin_amdgcn_s_setprio(1);
    #pragma unroll
    for (int mi = 0; mi < 4; ++mi)
      #pragma unroll
      for (int ni = 0; ni < 4; ++ni)
        acc[g0 + mi][ni] = __builtin_amdgcn_mfma_f32_16x16x32_bf16(af[mi], bfr[ni], acc[g0 + mi][ni], 0, 0, 0);
    __builtin_amdgcn_s_setprio(0);
  };

  const int nt = K >> 6;
  stageHalf(0, 0, 0, 0);
  stageHalf(0, 0, 1, 0);
  stageHalf(0, 1, 0, 0);
  stageHalf(0, 1, 1, 0);
  if (nt > 1) {
    stageHalf(1, 1, 0, 1);
    stageHalf(1, 1, 1, 1);
    asm volatile("s_waitcnt vmcnt(4)" ::: "memory");
  } else {
    asm volatile("s_waitcnt vmcnt(0)" ::: "memory");
  }
  BAR;

  bf16x8 bK0[4], bK1[4], af[4];
  for (int t = 0; t < nt; ++t) {
    const int c = t & 1, cn = c ^ 1;
    #pragma unroll
    for (int i = 0; i < 4; ++i) bK0[i] = readB(c, i, 0);
    #pragma unroll
    for (int i = 0; i < 4; ++i) af[i] = readA(c, i, 0);
    if (t + 1 < nt) stageHalf(cn, 0, 0, t + 1);
    BAR;
    mfma4(0, af, bK0);
    BAR;
    #pragma unroll
    for (int i = 0; i < 4; ++i) bK1[i] = readB(c, i, 1);
    #pragma unroll
    for (int i = 0; i < 4; ++i) af[i] = readA(c, 4 + i, 0);
    if (t + 1 < nt) stageHalf(cn, 0, 1, t + 1);
    BAR;
    mfma4(4, af, bK0);
    BAR;
    #pragma unroll
    for (int i = 0; i < 4; ++i) af[i] = readA(c, i, 1);
    if (t + 2 < nt) stageHalf(c, 1, 0, t + 2);
    BAR;
    mfma4(0, af, bK1);
    BAR;
    #pragma unroll
    for (int i = 0; i < 4; ++i) af[i] = readA(c, 4 + i, 1);
    if (t + 2 < nt) {
      stageHalf(c, 1, 1, t + 2);
      asm volatile("s_waitcnt vmcnt(4)" ::: "memory");
    } else {
      asm volatile("s_waitcnt vmcnt(0)" ::: "memory");
    }
    BAR;
    mfma4(4, af, bK1);
    BAR;
  }

  const long coff = FCM ? 0 : (long)z * strideC;
  int kval = 0, bb_ = 0;
  if (EPI == 2) { bb_ = z / NC_; kval = kvp[bb_]; }
  #pragma unroll
  for (int mi = 0; mi < 8; ++mi) {
    #pragma unroll
    for (int ni = 0; ni < 4; ++ni) {
      int n = n0 + wn * 64 + ni * 16 + lr;
      if (n >= Nstore) continue;
      float badd = 0.f;
      if (EPI == 0) {
        const float* bp = (FCM && set1) ? bias2 : bias1;
        if (bp) badd = bp[n];
      }
      if (EPI == 2) badd = bias1[z * NK + n] + tkv[bb_ * NK + n];
      #pragma unroll
      for (int r4 = 0; r4 < 4; ++r4) {
        int m = m0 + wm * 128 + mi * 16 + kh * 4 + r4;
        if (m >= Mstore) continue;
        float v = acc[mi][ni][r4] + badd;
        if (EPI == 2) {
          v += tkv[bb_ * NK + m];
          if (!(n < m && n < kval)) v += NEGV;
        }
        if (OBF16) ((__hip_bfloat16*)Cv)[coff + (long)m * ldc + n] = __float2bfloat16(v);
        else       ((float*)Cv)[coff + (long)m * ldc + n] = v;
      }
    }
  }
}

// ============ 128x128 8-wave GEMM, BK=64, dbuf 64KB LDS, 2 blocks/CU, batched-z ============
// z addressing: pA = A + z*strideA ; pB = B + (bmod7 ? z%7 : z)*strideB ; C += z*strideC.
// se/s2/FC callers pass strides=0 (z=0). Vcat passes per-z strides.
template<bool OBF16, int EPI>
__global__ __launch_bounds__(512, 4) void k_gemm2b(
    const __hip_bfloat16* __restrict__ A,
    const __hip_bfloat16* __restrict__ B,
    void* __restrict__ Cv, const float* __restrict__ bias1, const float* __restrict__ bias2,
    int K, int nbn, int ldc, int Mstore, int Nstore,
    long strideA, long strideB, int bmod7, long strideC)
{
  __shared__ __align__(16) char lds[2][32768];   // per buf: A[0,16K) B[16K,32K)
  const int tid = threadIdx.x;
  const int z = blockIdx.z;
  const int nwg = gridDim.x;
  const int xcd = blockIdx.x & 7, loc = blockIdx.x >> 3;
  const int q = nwg >> 3, rr = nwg & 7;
  const int wg = (xcd < rr ? xcd * (q + 1) : rr * (q + 1) + (xcd - rr) * q) + loc;
  const int bm = wg / nbn, bn = wg % nbn;
  const int m0 = bm * 128, n0 = bn * 128;
  const long Kb = (long)K * 2;
  const __hip_bfloat16* pA = A + (long)z * strideA;
  const __hip_bfloat16* pB = B + (long)(bmod7 ? (z % 7) : z) * strideB;
  const int wave = tid >> 6, lane = tid & 63;
  const int wm = wave >> 2, wn = wave & 3;
  const int lr = lane & 15, kh = lane >> 4;

  f32x4 acc[4][2];
  #pragma unroll
  for (int i = 0; i < 4; ++i)
    #pragma unroll
    for (int j = 0; j < 2; ++j)
      #pragma unroll
      for (int r4 = 0; r4 < 4; ++r4) acc[i][j][r4] = 0.0f;

  auto stage = [&](int bb, int kt) {
    const long kbyte = (long)kt * 128;
    const char* bA = (const char*)pA + (long)m0 * Kb;
    const char* bB = (const char*)pB + (long)n0 * Kb;
    #pragma unroll
    for (int j = 0; j < 2; ++j) {
      int off = j * 8192 + tid * 16;
      int row = off >> 7, col = off & 127;
      int gc = col ^ ((row & 7) << 4);
      gload_lds16(bA + (long)row * Kb + kbyte + gc, &lds[bb][row * 128 + col]);
    }
    #pragma unroll
    for (int j = 0; j < 2; ++j) {
      int off = j * 8192 + tid * 16;
      int row = off >> 7, col = off & 127;
      int gc = col ^ ((row & 7) << 4);
      gload_lds16(bB + (long)row * Kb + kbyte + gc, &lds[bb][16384 + row * 128 + col]);
    }
  };
  auto readA = [&](int c, int g, int kk) -> bf16x8 {
    int row = wm * 64 + g * 16 + lr;
    int colb = kk * 64 + kh * 16;
    return *(const bf16x8*)&lds[c][row * 128 + (colb ^ ((row & 7) << 4))];
  };
  auto readB = [&](int c, int ni, int kk) -> bf16x8 {
    int row = wn * 32 + ni * 16 + lr;
    int colb = kk * 64 + kh * 16;
    return *(const bf16x8*)&lds[c][16384 + row * 128 + (colb ^ ((row & 7) << 4))];
  };

  const int nt = K >> 6;
  stage(0, 0);
  asm volatile("s_waitcnt vmcnt(0)" ::: "memory");
  BAR;

  for (int t = 0; t < nt; ++t) {
    const int c = t & 1, cn = c ^ 1;
    if (t + 1 < nt) stage(cn, t + 1);
    bf16x8 af[4], bfr[2];
    #pragma unroll
    for (int kk = 0; kk < 2; ++kk) {
      #pragma unroll
      for (int i = 0; i < 4; ++i) af[i] = readA(c, i, kk);
      #pragma unroll
      for (int i = 0; i < 2; ++i) bfr[i] = readB(c, i, kk);
      __builtin_amdgcn_s_setprio(1);
      #pragma unroll
      for (int mi = 0; mi < 4; ++mi)
        #pragma unroll
        for (int ni = 0; ni < 2; ++ni)
          acc[mi][ni] = __builtin_amdgcn_mfma_f32_16x16x32_bf16(af[mi], bfr[ni], acc[mi][ni], 0, 0, 0);
      __builtin_amdgcn_s_setprio(0);
    }
    asm volatile("s_waitcnt vmcnt(0)" ::: "memory");
    BAR;
  }

  const long coff = (long)z * strideC;
  #pragma unroll
  for (int mi = 0; mi < 4; ++mi) {
    #pragma unroll
    for (int ni = 0; ni < 2; ++ni) {
      int n = n0 + wn * 32 + ni * 16 + lr;
      if (n >= Nstore) continue;
      float badd = 0.f;
      if (EPI == 0) { if (bias1) badd = bias1[n]; }
      if (EPI == 1) badd = (n >= 1024) ? bias2[n - 1024] : bias1[n];
      #pragma unroll
      for (int r4 = 0; r4 < 4; ++r4) {
        int m = m0 + wm * 64 + mi * 16 + kh * 4 + r4;
        if (m >= Mstore) continue;
        float v = acc[mi][ni][r4] + badd;
        if (OBF16) ((__hip_bfloat16*)Cv)[coff + (long)m * ldc + n] = __float2bfloat16(v);
        else       ((float*)Cv)[coff + (long)m * ldc + n] = v;
      }
    }
  }
}

// ---------- pack split3 ----------
template<bool APAT>
__global__ __launch_bounds__(256) void k_packsplit3(const float* __restrict__ s1, long stride1,
                                                    const float* __restrict__ s2, int split,
                                                    __hip_bfloat16* __restrict__ dst) {
  long idx4 = ((long)blockIdx.x * 256 + threadIdx.x) * 4;
  int rrow = (int)(idx4 >> 10), c = (int)(idx4 & 1023);
  const float* src = (rrow < split) ? s1 + (long)rrow * stride1 + c
                                    : s2 + (long)(rrow - split) * 1024 + c;
  float4 v = *(const float4*)src;
  float f[4] = {v.x, v.y, v.z, v.w};
  unsigned short h[4], l4[4];
  #pragma unroll
  for (int i = 0; i < 4; ++i) {
    h[i] = f2bf(f[i]);
    l4[i] = f2bf(f[i] - bf2f(h[i]));
  }
  unsigned short* d = (unsigned short*)dst + (long)rrow * 3072;
  ushort4 hv = {h[0], h[1], h[2], h[3]};
  ushort4 lv = {l4[0], l4[1], l4[2], l4[3]};
  *(ushort4*)(d + c)        = hv;
  *(ushort4*)(d + 1024 + c) = APAT ? hv : lv;
  *(ushort4*)(d + 2048 + c) = APAT ? lv : hv;
}

// ---------- dual f32 -> bf16 vector cast ----------
__global__ __launch_bounds__(256) void k_cast4d(const float* __restrict__ x0,
                                                __hip_bfloat16* __restrict__ y0,
                                                const float* __restrict__ x1,
                                                __hip_bfloat16* __restrict__ y1, long n4) {
  long i = (long)blockIdx.x * 256 + threadIdx.x;
  if (i >= n4) return;
  const float* x = blockIdx.y ? x1 : x0;
  __hip_bfloat16* y = blockIdx.y ? y1 : y0;
  float4 v = ((const float4*)x)[i];
  ushort4 o = {f2bf(v.x), f2bf(v.y), f2bf(v.z), f2bf(v.w)};
  ((ushort4*)y)[i] = o;
}

// ---------- pack Bbig[cat][n(2048)][k(2048)] ----------
__global__ __launch_bounds__(256) void k_packBbig(const float* __restrict__ Ws2s,
                                                  const float* __restrict__ We2e,
                                                  const float* __restrict__ Ws2e,
                                                  const float* __restrict__ We2s,
                                                  __hip_bfloat16* __restrict__ dst) {
  long idx4 = ((long)blockIdx.x * 256 + threadIdx.x) * 4;
  long rowid = idx4 >> 11;
  int c = (int)(idx4 & 2047);
  int cat = (int)(rowid >> 11);
  int n = (int)(rowid & 2047);
  const float* src;
  if (n < 1024) src = (c < 1024) ? Ws2s + ((long)cat * 1024 + n) * 1024 + c
                                 : Ws2e + ((long)cat * 1024 + n) * 1024 + (c - 1024);
  else          src = (c < 1024) ? We2s + ((long)cat * 1024 + (n - 1024)) * 1024 + c
                                 : We2e + ((long)cat * 1024 + (n - 1024)) * 1024 + (c - 1024);
  float4 v = *(const float4*)src;
  ushort4 o = {f2bf(v.x), f2bf(v.y), f2bf(v.z), f2bf(v.w)};
  *(ushort4*)((unsigned short*)dst + idx4) = o;
}

// ---------- fused GELU+LN+rowdot both halves; s-half split3-packs ----------
__global__ __launch_bounds__(512) void k_ln_se(float* __restrict__ se,
                                               const float* __restrict__ sg, const float* __restrict__ sbe,
                                               const float* __restrict__ eg, const float* __restrict__ ebe,
                                               const float* __restrict__ msw, const float* __restrict__ msb,
                                               const float* __restrict__ mew, const float* __restrict__ meb,
                                               float* __restrict__ smv, float* __restrict__ emv,
                                               __hip_bfloat16* __restrict__ ssp) {
  int r = blockIdx.x;
  int tid = threadIdx.x;
  int half = tid >> 8;
  int c4 = tid & 255;
  int w8 = tid >> 6;
  const float* g    = half ? eg : sg;
  const float* beta = half ? ebe : sbe;
  const float* wv   = half ? mew : msw;
  float4* rowp = (float4*)(se + (long)r * 2048 + half * 1024);
  float4 x = rowp[c4];
  float v[4] = {gelu_exact(x.x), gelu_exact(x.y), gelu_exact(x.z), gelu_exact(x.w)};
  float s = v[0] + v[1] + v[2] + v[3];
  float s2 = v[0]*v[0] + v[1]*v[1] + v[2]*v[2] + v[3]*v[3];
  __shared__ float red0[8], red1[8];
  for (int off = 32; off; off >>= 1) { s += __shfl_xor(s, off); s2 += __shfl_xor(s2, off); }
  if ((tid & 63) == 0) { red0[w8] = s; red1[w8] = s2; }
  __syncthreads();
  s  = red0[half*4] + red0[half*4+1] + red0[half*4+2] + red0[half*4+3];
  s2 = red1[half*4] + red1[half*4+1] + red1[half*4+2] + red1[half*4+3];
  float mu  = s / 1024.0f;
  float var = s2 / 1024.0f - mu * mu;
  float inv = 1.0f / sqrtf(var + 1e-5f);
  float4 gg = ((const float4*)g)[c4], bb = ((const float4*)beta)[c4];
  float y[4] = {(v[0]-mu)*inv*gg.x + bb.x, (v[1]-mu)*inv*gg.y + bb.y,
                (v[2]-mu)*inv*gg.z + bb.z, (v[3]-mu)*inv*gg.w + bb.w};
  float4 w4 = ((const float4*)wv)[c4];
  float d = y[0]*w4.x + y[1]*w4.y + y[2]*w4.z + y[3]*w4.w;
  for (int off = 32; off; off >>= 1) d += __shfl_xor(d, off);
  __syncthreads();
  if ((tid & 63) == 0) red0[w8] = d;
  __syncthreads();
  if ((tid & 255) == 0) {
    float dv = red0[half*4] + red0[half*4+1] + red0[half*4+2] + red0[half*4+3];
    if (half == 0) smv[r] = dv + msb[0];
    else           emv[r] = dv + meb[0];
  }
  if (half == 0) {
    unsigned short h[4], l4[4];
    #pragma unroll
    for (int i = 0; i < 4; ++i) { h[i] = f2bf(y[i]); l4[i] = f2bf(y[i] - bf2f(h[i])); }
    ushort4 hv = {h[0], h[1], h[2], h[3]};
    ushort4 lv = {l4[0], l4[1], l4[2], l4[3]};
    unsigned short* dst = (unsigned short*)ssp + (long)r * 3072 + c4 * 4;
    *(ushort4*)dst          = hv;
    *(ushort4*)(dst + 1024) = hv;
    *(ushort4*)(dst + 2048) = lv;
  } else {
    float4 yo = {y[0], y[1], y[2], y[3]};
    rowp[c4] = yo;
  }
}

// ---------- GELU+LN over 7168 (bf16 in) -> a_cat halves; grid 3584 ----------
__global__ __launch_bounds__(256) void k_gelu_ln_cats(const __hip_bfloat16* __restrict__ h,
                                                      const float* __restrict__ sg,
                                                      const float* __restrict__ sbe,
                                                      const float* __restrict__ eg,
                                                      const float* __restrict__ ebe,
                                                      __hip_bfloat16* __restrict__ a_cat) {
  int r = blockIdx.x;
  int half = (r >= 2 * KP) ? 1 : 0;
  int r2 = r - half * 2 * KP;
  int b = (r2 >= KP) ? 1 : 0, k = r2 - KP * b;
  const float* g    = half ? eg : sg;
  const float* beta = half ? ebe : sbe;
  const ushort4* row = (const ushort4*)((const unsigned short*)h + (long)r * 7168);
  float v[28];
  float s = 0.f, s2 = 0.f;
  #pragma unroll
  for (int j = 0; j < 7; ++j) {
    ushort4 u = row[threadIdx.x + 256 * j];
    #pragma unroll
    for (int e = 0; e < 4; ++e) {
      float x = bf2f(((const unsigned short*)&u)[e]);
      float ge = gelu_exact(x);
      v[j * 4 + e] = ge; s += ge; s2 += ge * ge;
    }
  }
  __shared__ float red0[4], red1[4];
  for (int off = 32; off; off >>= 1) { s += __shfl_xor(s, off); s2 += __shfl_xor(s2, off); }
  int w = threadIdx.x >> 6;
  if ((threadIdx.x & 63) == 0) { red0[w] = s; red1[w] = s2; }
  __syncthreads();
  s  = red0[0] + red0[1] + red0[2] + red0[3];
  s2 = red1[0] + red1[1] + red1[2] + red1[3];
  float mu  = s / 7168.0f;
  float var = s2 / 7168.0f - mu * mu;
  float inv = 1.0f / sqrtf(var + 1e-5f);
  #pragma unroll
  for (int j = 0; j < 7; ++j) {
    int c0 = (threadIdx.x + 256 * j) * 4;
    int n = c0 >> 10, f = c0 & 1023;
    unsigned short o[4];
    #pragma unroll
    for (int e = 0; e < 4; ++e)
      o[e] = f2bf((v[j * 4 + e] - mu) * inv * g[c0 + e] + beta[c0 + e]);
    ushort4 ov = {o[0], o[1], o[2], o[3]};
    *(ushort4*)((unsigned short*)a_cat + ((long)((b * NC_ + n) * NK + k)) * 2048 + half * 1024 + f) = ov;
  }
}

// ---------- banded scores ----------
__global__ __launch_bounds__(512) void k_band(const float* __restrict__ s2m,
                                              const float* __restrict__ se,
                                              const float* __restrict__ smv,
                                              const float* __restrict__ emv,
                                              float* __restrict__ band) {
  __shared__ float ebuf[2][1024];
  int blk = blockIdx.x;
  int b = blk >> 8;
  int s0 = (blk & 255) * 8;
  int w = threadIdx.x >> 6, l = threadIdx.x & 63;
  int s = s0 + w;
  int tid = threadIdx.x;
  float sreg[16];
  const float* sp = s2m + ((long)(b << 11) + s) * 1024;
  #pragma unroll
  for (int qq = 0; qq < 16; ++qq) sreg[qq] = sp[l + 64 * qq];
  float myS = smv[(b << 11) + s];
  if (l < 32) {
    int j = l;
    if (j >= 30 || s + j >= S_)
      band[((long)(b << 11) + s) * 32 + j] = -3.0e38f;
  }
  {
    const float* ep = se + ((long)(b << 11) + s0) * 2048 + 1024;
    ebuf[0][tid * 2]     = ep[tid * 2];
    ebuf[0][tid * 2 + 1] = ep[tid * 2 + 1];
  }
  for (int it = 0; it < 37; ++it) {
    int t = s0 + it;
    __syncthreads();
    if (it + 1 < 37 && s0 + it + 1 < S_) {
      const float* ep = se + ((long)(b << 11) + s0 + it + 1) * 2048 + 1024;
      ebuf[(it + 1) & 1][tid * 2]     = ep[tid * 2];
      ebuf[(it + 1) & 1][tid * 2 + 1] = ep[tid * 2 + 1];
    }
    int j = t - s;
    if (t < S_ && j >= 0 && j < 30) {
      const float* eb = ebuf[it & 1];
      float acc = 0.f;
      #pragma unroll
      for (int qq = 0; qq < 16; ++qq) acc += sreg[qq] * eb[l + 64 * qq];
      for (int off = 32; off; off >>= 1) acc += __shfl_xor(acc, off);
      if (l == 0)
        band[((long)(b << 11) + s) * 32 + j] = acc + myS + emv[(b << 11) + t];
    }
  }
}

// ================= parallel exact top-k =================
__global__ __launch_bounds__(1024) void k_tkhist(const float* __restrict__ band,
                                                 unsigned* __restrict__ ghist) {
  int b = blockIdx.y;
  const float* bb = band + (long)b * 65536;
  __shared__ unsigned lh[4096];
  int tid = threadIdx.x;
  #pragma unroll
  for (int j = 0; j < 4; ++j) lh[tid + j * 1024] = 0;
  __syncthreads();
  int base = blockIdx.x * 4096;
  #pragma unroll
  for (int j = 0; j < 4; ++j) {
    unsigned key = fkey(bb[base + tid + j * 1024]);
    atomicAdd(&lh[key >> 20], 1u);
  }
  __syncthreads();
  #pragma unroll
  for (int j = 0; j < 4; ++j) {
    unsigned v = lh[tid + j * 1024];
    if (v) atomicAdd(&ghist[b * 4096 + tid + j * 1024], v);
  }
}

__global__ __launch_bounds__(1024) void k_tkscan(const unsigned* __restrict__ ghist,
                                                 const int* __restrict__ masks,
                                                 unsigned* __restrict__ sel) {
  int b = blockIdx.x;
  int tid = threadIdx.x;
  __shared__ unsigned cs[1024];
  __shared__ int red[16];
  __shared__ int sh_kv;
  int pm = masks[b * S_ + tid] + masks[b * S_ + 1024 + tid];
  for (int off = 32; off; off >>= 1) pm += __shfl_xor(pm, off);
  if ((tid & 63) == 0) red[tid >> 6] = pm;
  __syncthreads();
  if (tid == 0) {
    int msum = 0;
    for (int i = 0; i < 16; ++i) msum += red[i];
    int kv = (int)((float)msum * 0.4f);
    if (kv > MAXK) kv = MAXK;
    sh_kv = kv;
  }
  __syncthreads();
  int kv = sh_kv;
  unsigned hbin[4];
  unsigned ssum = 0;
  #pragma unroll
  for (int j = 0; j < 4; ++j) { hbin[j] = ghist[b * 4096 + tid * 4 + j]; ssum += hbin[j]; }
  cs[tid] = ssum;
  __syncthreads();
  for (int off = 1; off < 1024; off <<= 1) {
    unsigned add = (tid + off < 1024) ? cs[tid + off] : 0u;
    __syncthreads();
    cs[tid] += add;
    __syncthreads();
  }
  unsigned above = cs[tid] - ssum;
  if (kv > 0) {
    unsigned aa = above;
    for (int j = 3; j >= 0; --j) {
      if (aa < (unsigned)kv && aa + hbin[j] >= (unsigned)kv) sel[b * 2] = (unsigned)(tid * 4 + j);
      aa += hbin[j];
    }
  }
  if (tid == 0) {
    sel[b * 2 + 1] = (unsigned)kv;
    if (kv == 0) sel[b * 2] = 0xFFFFFFFFu;
  }
}

__global__ __launch_bounds__(1024) void k_tkcollect(const float* __restrict__ band,
                                                    const unsigned* __restrict__ sel,
                                                    unsigned* __restrict__ cand,
                                                    unsigned* __restrict__ gcnt) {
  int b = blockIdx.y;
  const float* bb = band + (long)b * 65536;
  unsigned thr = sel[b * 2];
  int base = blockIdx.x * 4096;
  int tid = threadIdx.x;
  #pragma unroll
  for (int j = 0; j < 4; ++j) {
    int i = base + tid + j * 1024;
    unsigned key = fkey(bb[i]);
    if ((key >> 20) >= thr) {
      unsigned p = atomicAdd(&gcnt[b], 1u);
      cand[(long)b * 65536 + p] = (unsigned)i;
    }
  }
}

__device__ __forceinline__ void bitonic1024(unsigned* buf) {
  int tid = threadIdx.x;
  __syncthreads();
  for (int k = 2; k <= 1024; k <<= 1)
    for (int j = k >> 1; j > 0; j >>= 1) {
      int ixj = tid ^ j;
      if (ixj > tid) {
        unsigned a = buf[tid], c = buf[ixj];
        bool up = ((tid & k) == 0);
        if (up ? (a > c) : (a < c)) { buf[tid] = c; buf[ixj] = a; }
      }
      __syncthreads();
    }
}

__global__ __launch_bounds__(1024) void k_tkfinal(const float* __restrict__ band,
                                                  const unsigned* __restrict__ cand,
                                                  const unsigned* __restrict__ gcnt,
                                                  const unsigned* __restrict__ sel,
                                                  int* __restrict__ starts, int* __restrict__ ends,
                                                  float* __restrict__ tk, int* __restrict__ kvalid_out) {
  int b = blockIdx.x;
  const float* bb = band + (long)b * 65536;
  const unsigned* cd = cand + (long)b * 65536;
  int nC = (int)gcnt[b];
  int kv = (int)sel[b * 2 + 1];
  __shared__ unsigned hist[256];
  __shared__ int sh_digit, sh_R;
  __shared__ unsigned cntG, cntE;
  __shared__ unsigned listG[832];
  __shared__ unsigned listE[1024];
  __shared__ unsigned buf[1024];
  int tid = threadIdx.x;

  unsigned prefix = 0;
  int R = kv;
  if (kv > 0) {
    for (int shift = 24; shift >= 0; shift -= 8) {
      if (tid < 256) hist[tid] = 0;
      __syncthreads();
      for (int j = tid; j < nC; j += 1024) {
        unsigned key = fkey(bb[cd[j]]);
        bool ok = (shift == 24) || ((key >> (shift + 8)) == (prefix >> (shift + 8)));
        if (ok) atomicAdd(&hist[(key >> shift) & 255u], 1u);
      }
      __syncthreads();
      if (tid == 0) {
        unsigned cum = 0; int d;
        for (d = 255; d >= 0; --d) {
          unsigned hc = hist[d];
          if (cum + hc >= (unsigned)R) break;
          cum += hc;
        }
        if (d < 0) d = 0;
        sh_digit = d; sh_R = R - (int)cum;
      }
      __syncthreads();
      prefix |= ((unsigned)sh_digit) << shift;
      R = sh_R;
      __syncthreads();
    }
  }
  if (tid == 0) { cntG = 0; cntE = 0; }
  __syncthreads();
  if (kv > 0) {
    for (int j = tid; j < nC; j += 1024) {
      unsigned i = cd[j];
      unsigned key = fkey(bb[i]);
      if (key > prefix) { unsigned p = atomicAdd(&cntG, 1u); if (p < 832) listG[p] = i; }
      else if (key == prefix) { unsigned p = atomicAdd(&cntE, 1u); if (p < 1024) listE[p] = i; }
    }
  }
  __syncthreads();
  int nG = (int)cntG, nE = (int)cntE, need = R;
  buf[tid] = (tid < nE) ? listE[tid] : 0xFFFFFFFFu;
  bitonic1024(buf);
  if (tid < need) listG[nG + tid] = buf[tid];
  __syncthreads();
  unsigned v2 = (tid < (unsigned)kv) ? listG[tid] : 0xFFFFFFFFu;
  __syncthreads();
  buf[tid] = v2;
  bitonic1024(buf);
  {
    int s, t; float val;
    if (tid < kv) {
      unsigned i = buf[tid];
      s = (int)(i >> 5); t = s + (int)(i & 31);
      val = bb[i];
    } else {
      s = S_ - 1; t = S_ - 1;
      val = bb[(S_ - 1) * 32 + 0];
    }
    starts[b * NK + tid] = s;
    ends[b * NK + tid] = t;
    tk[b * NK + tid] = val;
  }
  if (tid == 0) kvalid_out[b] = kv;
}

// ---------- gather span reps to bf16 ----------
__global__ __launch_bounds__(256) void k_gather(const float* __restrict__ emb,
                                                const int* __restrict__ starts,
                                                const int* __restrict__ ends,
                                                __hip_bfloat16* __restrict__ reps_s,
                                                __hip_bfloat16* __restrict__ reps_e) {
  int r = blockIdx.x;
  int b = (r >= KP) ? 1 : 0, k = r - KP * b;
  long ob = (long)r * 1024;
  const float4* ps = (const float4*)(emb + ((long)b * S_ + starts[b * NK + k]) * 1024);
  const float4* pe = (const float4*)(emb + ((long)b * S_ + ends[b * NK + k]) * 1024);
  unsigned short* ds = (unsigned short*)reps_s + ob;
  unsigned short* de = (unsigned short*)reps_e + ob;
  int c4 = threadIdx.x;
  float4 a = ps[c4], e = pe[c4];
  ushort4 oa = {f2bf(a.x), f2bf(a.y), f2bf(a.z), f2bf(a.w)};
  ushort4 oe = {f2bf(e.x), f2bf(e.y), f2bf(e.z), f2bf(e.w)};
  *(ushort4*)(ds + c4 * 4) = oa;
  *(ushort4*)(de + c4 * 4) = oe;
}

// ---------- antecedent bias vector ----------
__global__ __launch_bounds__(256) void k_bias(const __hip_bfloat16* __restrict__ a_cat,
                                              const float* __restrict__ Bs2s, const float* __restrict__ Be2e,
                                              const float* __restrict__ Bs2e, const float* __restrict__ Be2s,
                                              float* __restrict__ biasv) {
  int w = threadIdx.x >> 6, l = threadIdx.x & 63;
  int rid = blockIdx.x * 4 + w;
  if (rid >= Z_ * KP) return;
  int z = rid / KP, li = rid - z * KP;
  int cat = z % NC_;
  const unsigned short* ar = (const unsigned short*)a_cat + ((long)z * NK + li) * 2048;
  const float* b1 = Bs2s + cat * 1024;
  const float* b2 = Be2s + cat * 1024;
  const float* b3 = Be2e + cat * 1024;
  const float* b4 = Bs2e + cat * 1024;
  float acc = 0.f;
  for (int qq = 0; qq < 16; ++qq) {
    int c = l + 64 * qq;
    acc += bf2f(ar[c]) * (b1[c] + b2[c]);
    acc += bf2f(ar[1024 + c]) * (b3[c] + b4[c]);
  }
  for (int off = 32; off; off >>= 1) acc += __shfl_xor(acc, off);
  if (l == 0) biasv[z * NK + li] = acc;
}

// =====================================================================
extern "C" void kernel_launch(void* const* d_in, const int* in_sizes, int n_in,
                              void* d_out, int out_size, void* d_ws, size_t ws_size,
                              hipStream_t stream) {
  const float* x_emb = (const float*)d_in[0];
  const int*   masks = (const int*)d_in[1];
  const float* smW  = (const float*)d_in[2];
  const float* smb  = (const float*)d_in[3];
  const float* smg  = (const float*)d_in[4];
  const float* smbe = (const float*)d_in[5];
  const float* emW  = (const float*)d_in[6];
  const float* embb = (const float*)d_in[7];
  const float* emg  = (const float*)d_in[8];
  const float* embe = (const float*)d_in[9];
  const float* msw  = (const float*)d_in[10];
  const float* msb  = (const float*)d_in[11];
  const float* mew  = (const float*)d_in[12];
  const float* meb  = (const float*)d_in[13];
  const float* s2eW = (const float*)d_in[14];
  const float* s2eb = (const float*)d_in[15];
  const float* csW  = (const float*)d_in[16];
  const float* csb  = (const float*)d_in[17];
  const float* csg  = (const float*)d_in[18];
  const float* csbe = (const float*)d_in[19];
  const float* ceW  = (const float*)d_in[20];
  const float* ceb  = (const float*)d_in[21];
  const float* ceg  = (const float*)d_in[22];
  const float* cebe = (const float*)d_in[23];
  const float* Ws2s = (const float*)d_in[24];
  const float* We2e = (const float*)d_in[25];
  const float* Ws2e = (const float*)d_in[26];
  const float* We2s = (const float*)d_in[27];
  const float* Bs2s = (const float*)d_in[28];
  const float* Be2e = (const float*)d_in[29];
  const float* Bs2e = (const float*)d_in[30];
  const float* Be2s = (const float*)d_in[31];
  float* outp = (float*)d_out;
  char* ws = (char*)d_ws;
  (void)in_sizes; (void)n_in; (void)out_size; (void)ws_size;

  const size_t o_embsp = 0;
  const size_t o_bse   = 25165824;
  const size_t o_ssp   = 0;
  const size_t o_s2W   = 25165824;
  const size_t o_repss = 0;
  const size_t o_repse = 4194304;
  const size_t o_csWb  = 8388608;
  const size_t o_ceWb  = 23068672;   // = o_csWb + 7168*1024*2 bytes (contiguous after csWb)
  const size_t o_Bbig  = 0;
  const size_t o_se    = 37748736;
  const size_t o_s2    = 71303168;
  const size_t o_h     = 88080384;   // h_all bf16 [3584][7168] ; later Vcat bf16 [14][1024][2048]
  const size_t o_acat  = 146800640;
  const size_t o_smv   = 205520896;
  const size_t o_emv   = o_smv + 16384;
  const size_t o_band  = o_emv + 16384;
  const size_t o_starts= o_band + 524288;
  const size_t o_ends  = o_starts + 8192;
  const size_t o_tk    = o_ends + 8192;
  const size_t o_kv    = o_tk + 8192;
  const size_t o_biasv = o_kv + 256;
  const size_t o_ghist = o_biasv + 61440;
  const size_t o_gcnt  = o_ghist + 32768;
  const size_t o_sel   = o_gcnt + 256;
  const size_t o_cand  = o_sel + 256;

  __hip_bfloat16* embsp = (__hip_bfloat16*)(ws + o_embsp);
  __hip_bfloat16* bse   = (__hip_bfloat16*)(ws + o_bse);
  __hip_bfloat16* ssp   = (__hip_bfloat16*)(ws + o_ssp);
  __hip_bfloat16* s2Wsp = (__hip_bfloat16*)(ws + o_s2W);
  __hip_bfloat16* repss = (__hip_bfloat16*)(ws + o_repss);
  __hip_bfloat16* repse = (__hip_bfloat16*)(ws + o_repse);
  __hip_bfloat16* csWb  = (__hip_bfloat16*)(ws + o_csWb);
  __hip_bfloat16* ceWb  = (__hip_bfloat16*)(ws + o_ceWb);
  __hip_bfloat16* Bbig  = (__hip_bfloat16*)(ws + o_Bbig);
  float* se_buf = (float*)(ws + o_se);
  float* s2_buf = (float*)(ws + o_s2);
  __hip_bfloat16* h_all = (__hip_bfloat16*)(ws + o_h);
  __hip_bfloat16* Vcat  = (__hip_bfloat16*)(ws + o_h);
  __hip_bfloat16* a_cat = (__hip_bfloat16*)(ws + o_acat);
  float* smv_p = (float*)(ws + o_smv);
  float* emv_p = (float*)(ws + o_emv);
  float* band_p = (float*)(ws + o_band);
  int* starts_p = (int*)(ws + o_starts);
  int* ends_p = (int*)(ws + o_ends);
  float* tk_p = (float*)(ws + o_tk);
  int* kv_p = (int*)(ws + o_kv);
  float* biasv_p = (float*)(ws + o_biasv);
  unsigned* ghist_p = (unsigned*)(ws + o_ghist);
  unsigned* gcnt_p = (unsigned*)(ws + o_gcnt);
  unsigned* sel_p = (unsigned*)(ws + o_sel);
  unsigned* cand_p = (unsigned*)(ws + o_cand);

  // ---- stage A ----
  k_packsplit3<true ><<<4096, 256, 0, stream>>>(x_emb, 1024, x_emb, 4096, embsp);
  k_packsplit3<false><<<2048, 256, 0, stream>>>(smW, 1024, emW, 1024, bse);
  k_gemm2b<false, 1><<<512, 512, 0, stream>>>(embsp, bse,
      se_buf, smb, embb, 3072, 16, 2048, 4096, 2048, 0, 0, 0, 0);
  k_ln_se<<<4096, 512, 0, stream>>>(se_buf, smg, smbe, emg, embe, msw, msb, mew, meb,
                                    smv_p, emv_p, ssp);

  // ---- stage C ----
  k_packsplit3<false><<<1024, 256, 0, stream>>>(s2eW, 1024, s2eW, 1024, s2Wsp);
  k_gemm2b<false, 0><<<256, 512, 0, stream>>>(ssp, s2Wsp,
      s2_buf, s2eb, nullptr, 3072, 8, 1024, 4096, 1024, 0, 0, 0, 0);
  k_band<<<512, 512, 0, stream>>>(s2_buf, se_buf, smv_p, emv_p, band_p);

  // ---- stage D: parallel exact top-k ----
  hipMemsetAsync(ws + o_ghist, 0, 33024, stream);   // ghist + gcnt
  k_tkhist<<<dim3(16, 2), 1024, 0, stream>>>(band_p, ghist_p);
  k_tkscan<<<2, 1024, 0, stream>>>(ghist_p, masks, sel_p);
  k_tkcollect<<<dim3(16, 2), 1024, 0, stream>>>(band_p, sel_p, cand_p, gcnt_p);
  k_tkfinal<<<2, 1024, 0, stream>>>(band_p, cand_p, gcnt_p, sel_p,
                                    starts_p, ends_p, tk_p, kv_p);

  // ---- stage E/F: gather + merged FC on deep kernel (M = 3584 block-diag) ----
  k_gather<<<2 * KP, 256, 0, stream>>>(x_emb, starts_p, ends_p, repss, repse);
  k_cast4d<<<dim3(7168, 2), 256, 0, stream>>>(csW, csWb, ceW, ceWb, 1835008);
  k_gemm8<true, 0, true><<<dim3(392, 1, 1), 512, 0, stream>>>(repss, repse, csWb,
      h_all, csb, ceb, nullptr, nullptr, 1024, 28, 0, (long)7168 * 1024, 0, 0,
      7168, 3584, 7168, 2 * KP);
  k_packBbig<<<28672, 256, 0, stream>>>(Ws2s, We2e, Ws2e, We2s, Bbig);
  k_gelu_ln_cats<<<3584, 256, 0, stream>>>(h_all, csg, csbe, ceg, cebe, a_cat);

  // ---- stage G: Vcat on z-extended k_gemm2b (2 blocks/CU, 1792 blocks) ----
  k_gemm2b<true, 0><<<dim3(128, 1, Z_), 512, 0, stream>>>(a_cat, Bbig,
      Vcat, nullptr, nullptr, 2048, 16, 2048, NK, 2048,
      (long)NK * 2048, (long)2048 * 2048, 1, (long)NK * 2048);
  k_bias<<<(Z_ * KP) / 4, 256, 0, stream>>>(a_cat, Bs2s, Be2e, Bs2e, Be2s, biasv_p);
  k_gemm8<false, 2, false><<<dim3(16, 1, Z_), 512, 0, stream>>>(a_cat, nullptr, Vcat,
      outp, biasv_p, nullptr, tk_p, kv_p, 2048, 4, (long)NK * 2048,
      (long)NK * 2048, 0, (long)MAXK * MAXK, MAXK, MAXK, MAXK, 0);
}

// Round 16
// 654.336 us; speedup vs baseline: 1.0554x; 1.0554x over previous
//
#include <hip/hip_runtime.h>
#include <hip/hip_bf16.h>
#include <math.h>

// ---- problem constants ----
#define S_    2048
#define NC_   7
#define MAXK  819
#define NK    1024          // a_cat/Vcat row stride per z
#define KP    896           // trimmed valid top-k rows (7*128)
#define Z_    14            // B*NUM_CATS
#define NEGV  (-10000.0f)

typedef __attribute__((ext_vector_type(8))) short bf16x8;
typedef __attribute__((ext_vector_type(4))) float f32x4;

#define CFENCE asm volatile("" ::: "memory")
#define BAR    do { CFENCE; __builtin_amdgcn_s_barrier(); CFENCE; } while (0)

__device__ __forceinline__ void gload_lds16(const void* g, void* l) {
  __builtin_amdgcn_global_load_lds((const __attribute__((address_space(1))) unsigned int*)g,
                                   (__attribute__((address_space(3))) unsigned int*)l, 16, 0, 0);
}

__device__ __forceinline__ float gelu_exact(float x) {
  return 0.5f * x * (1.0f + erff(x * 0.70710678118654752f));
}
__device__ __forceinline__ unsigned short f2bf(float x) {
  __hip_bfloat16 h = __float2bfloat16(x);
  return *(unsigned short*)&h;
}
__device__ __forceinline__ float bf2f(unsigned short u) {
  __hip_bfloat16 h; *(unsigned short*)&h = u;
  return __bfloat162float(h);
}
__device__ __forceinline__ unsigned fkey(float f) {
  unsigned u = __float_as_uint(f);
  return (u & 0x80000000u) ? ~u : (u | 0x80000000u);
}

// ===== 256x256 8-wave GEMM, BK=64, deep pipeline + reg-pipelined fragments (r11 loop, audited) =====
// R0: read ALL B(c) (8 frags) + A g0-3 kk0.
// M0: stage A0(t+1)->cn ; read-ahead A g4-7 kk0 ; MFMA0 ; BAR
// M1: stage A1(t+1)->cn ; read-ahead A g0-3 kk1 ; MFMA1 ; lgkmcnt(0) (WAR fence) ; BAR
// M2: stage B0(t+2)->c  ; read-ahead A g4-7 kk1 ; MFMA2 ; BAR
// M3: stage B1(t+2)->c  ; vmcnt(4) (A(t+1),B(t+1) landed) ; MFMA3 ; BAR
template<bool OBF16, int EPI, bool FCM>
__global__ __launch_bounds__(512, 2) void k_gemm8(
    const __hip_bfloat16* __restrict__ A, const __hip_bfloat16* __restrict__ A2,
    const __hip_bfloat16* __restrict__ B,
    void* __restrict__ Cv, const float* __restrict__ bias1, const float* __restrict__ bias2,
    const float* __restrict__ tkv, const int* __restrict__ kvp,
    int K, int nbn, long strideA, long strideB, int bmod7, long strideC,
    int ldc, int Mstore, int Nstore, int Msplit)
{
  __shared__ __align__(16) char lds[2][65536];   // per buf: A[0,32K) B[32K,64K)
  const int tid = threadIdx.x;
  const int z = blockIdx.z;
  const int nwg = gridDim.x;
  const int xcd = blockIdx.x & 7, loc = blockIdx.x >> 3;
  const int q = nwg >> 3, rr = nwg & 7;
  const int wg = (xcd < rr ? xcd * (q + 1) : rr * (q + 1) + (xcd - rr) * q) + loc;
  const int bm = wg / nbn, bn = wg % nbn;
  const int m0 = bm * 256, n0 = bn * 256;
  const bool set1 = FCM && (m0 >= Msplit);
  const __hip_bfloat16* pA = FCM ? (set1 ? (A2 - (long)Msplit * K) : A)
                                 : (A + (long)z * strideA);
  const __hip_bfloat16* pB = FCM ? (B + (set1 ? strideB : 0))
                                 : (B + (long)(bmod7 ? (z % 7) : z) * strideB);
  const int wave = tid >> 6, lane = tid & 63;
  const int wm = wave >> 2, wn = wave & 3;
  const int lr = lane & 15, kh = lane >> 4;
  const long Kb = (long)K * 2;

  f32x4 acc[8][4];
  #pragma unroll
  for (int i = 0; i < 8; ++i)
    #pragma unroll
    for (int j = 0; j < 4; ++j)
      #pragma unroll
      for (int r4 = 0; r4 < 4; ++r4) acc[i][j][r4] = 0.0f;

  auto stageHalf = [&](int bb, int isB, int rh, int kt) {
    const long kbyte = (long)kt * 128;
    const char* basep = isB ? (const char*)pB + (long)(n0 + rh * 128) * Kb
                            : (const char*)pA + (long)(m0 + rh * 128) * Kb;
    #pragma unroll
    for (int j = 0; j < 2; ++j) {
      int off = j * 8192 + tid * 16;
      int row = off >> 7, col = off & 127;
      int gc = col ^ (((rh * 128 + row) & 7) << 4);
      gload_lds16(basep + (long)row * Kb + kbyte + gc,
                  &lds[bb][isB * 32768 + (rh * 128 + row) * 128 + col]);
    }
  };
  auto readA = [&](int c, int g, int kk) -> bf16x8 {
    int row = wm * 128 + g * 16 + lr;
    int colb = kk * 64 + kh * 16;
    return *(const bf16x8*)&lds[c][row * 128 + (colb ^ ((row & 7) << 4))];
  };
  auto readB = [&](int c, int ni, int kk) -> bf16x8 {
    int row = wn * 64 + ni * 16 + lr;
    int colb = kk * 64 + kh * 16;
    return *(const bf16x8*)&lds[c][32768 + row * 128 + (colb ^ ((row & 7) << 4))];
  };
  auto mfma4 = [&](int g0, bf16x8* af, bf16x8* bfr) {
    __builtin_amdgcn_s_setprio(1);
    #pragma unroll
    for (int mi = 0; mi < 4; ++mi)
      #pragma unroll
      for (int ni = 0; ni < 4; ++ni)
        acc[g0 + mi][ni] = __builtin_amdgcn_mfma_f32_16x16x32_bf16(af[mi], bfr[ni], acc[g0 + mi][ni], 0, 0, 0);
    __builtin_amdgcn_s_setprio(0);
  };

  const int nt = K >> 6;
  // prologue: A(0),B(0) -> buf0 ; B(1) -> buf1
  stageHalf(0, 0, 0, 0);
  stageHalf(0, 0, 1, 0);
  stageHalf(0, 1, 0, 0);
  stageHalf(0, 1, 1, 0);
  if (nt > 1) {
    stageHalf(1, 1, 0, 1);
    stageHalf(1, 1, 1, 1);
    asm volatile("s_waitcnt vmcnt(4)" ::: "memory");   // A(0),B(0) landed
  } else {
    asm volatile("s_waitcnt vmcnt(0)" ::: "memory");
  }
  BAR;

  bf16x8 bK0[4], bK1[4], aCur[4], aNext[4];
  for (int t = 0; t < nt; ++t) {
    const int c = t & 1, cn = c ^ 1;
    // ---- R0: all B(c) + A g0-3 kk0 ----
    #pragma unroll
    for (int i = 0; i < 4; ++i) bK0[i] = readB(c, i, 0);
    #pragma unroll
    for (int i = 0; i < 4; ++i) bK1[i] = readB(c, i, 1);
    #pragma unroll
    for (int i = 0; i < 4; ++i) aCur[i] = readA(c, i, 0);
    // ---- M0 ----
    if (t + 1 < nt) stageHalf(cn, 0, 0, t + 1);
    #pragma unroll
    for (int i = 0; i < 4; ++i) aNext[i] = readA(c, 4 + i, 0);
    mfma4(0, aCur, bK0);
    BAR;
    // ---- M1 ----
    if (t + 1 < nt) stageHalf(cn, 0, 1, t + 1);
    #pragma unroll
    for (int i = 0; i < 4; ++i) aCur[i] = readA(c, i, 1);
    mfma4(4, aNext, bK0);
    asm volatile("s_waitcnt lgkmcnt(0)" ::: "memory");  // all B(c)/A(c) ds_reads done before B-region overwrite
    BAR;
    // ---- M2 ----
    if (t + 2 < nt) stageHalf(c, 1, 0, t + 2);
    #pragma unroll
    for (int i = 0; i < 4; ++i) aNext[i] = readA(c, 4 + i, 1);
    mfma4(0, aCur, bK1);
    BAR;
    // ---- M3 ----
    if (t + 2 < nt) {
      stageHalf(c, 1, 1, t + 2);
      asm volatile("s_waitcnt vmcnt(4)" ::: "memory");   // A(t+1)+B(t+1) landed; B(t+2) in flight
    } else {
      asm volatile("s_waitcnt vmcnt(0)" ::: "memory");
    }
    mfma4(4, aNext, bK1);
    BAR;
  }

  const long coff = FCM ? 0 : (long)z * strideC;
  int kval = 0, bb_ = 0;
  if (EPI == 2) { bb_ = z / NC_; kval = kvp[bb_]; }
  #pragma unroll
  for (int mi = 0; mi < 8; ++mi) {
    #pragma unroll
    for (int ni = 0; ni < 4; ++ni) {
      int n = n0 + wn * 64 + ni * 16 + lr;
      if (n >= Nstore) continue;
      float badd = 0.f;
      if (EPI == 0) {
        const float* bp = (FCM && set1) ? bias2 : bias1;
        if (bp) badd = bp[n];
      }
      if (EPI == 2) badd = bias1[z * NK + n] + tkv[bb_ * NK + n];
      #pragma unroll
      for (int r4 = 0; r4 < 4; ++r4) {
        int m = m0 + wm * 128 + mi * 16 + kh * 4 + r4;
        if (m >= Mstore) continue;
        float v = acc[mi][ni][r4] + badd;
        if (EPI == 2) {
          v += tkv[bb_ * NK + m];
          if (!(n < m && n < kval)) v += NEGV;
        }
        if (OBF16) ((__hip_bfloat16*)Cv)[coff + (long)m * ldc + n] = __float2bfloat16(v);
        else       ((float*)Cv)[coff + (long)m * ldc + n] = v;
      }
    }
  }
}

// ============ 128x128 8-wave GEMM, BK=64, dbuf 64KB LDS (se / s2) ============
template<bool OBF16, int EPI>
__global__ __launch_bounds__(512, 4) void k_gemm2b(
    const __hip_bfloat16* __restrict__ A,
    const __hip_bfloat16* __restrict__ B,
    void* __restrict__ Cv, const float* __restrict__ bias1, const float* __restrict__ bias2,
    int K, int nbn, int ldc, int Mstore, int Nstore)
{
  __shared__ __align__(16) char lds[2][32768];   // per buf: A[0,16K) B[16K,32K)
  const int tid = threadIdx.x;
  const int nwg = gridDim.x;
  const int xcd = blockIdx.x & 7, loc = blockIdx.x >> 3;
  const int q = nwg >> 3, rr = nwg & 7;
  const int wg = (xcd < rr ? xcd * (q + 1) : rr * (q + 1) + (xcd - rr) * q) + loc;
  const int bm = wg / nbn, bn = wg % nbn;
  const int m0 = bm * 128, n0 = bn * 128;
  const long Kb = (long)K * 2;
  const int wave = tid >> 6, lane = tid & 63;
  const int wm = wave >> 2, wn = wave & 3;
  const int lr = lane & 15, kh = lane >> 4;

  f32x4 acc[4][2];
  #pragma unroll
  for (int i = 0; i < 4; ++i)
    #pragma unroll
    for (int j = 0; j < 2; ++j)
      #pragma unroll
      for (int r4 = 0; r4 < 4; ++r4) acc[i][j][r4] = 0.0f;

  auto stage = [&](int bb, int kt) {
    const long kbyte = (long)kt * 128;
    const char* bA = (const char*)A + (long)m0 * Kb;
    const char* bB = (const char*)B + (long)n0 * Kb;
    #pragma unroll
    for (int j = 0; j < 2; ++j) {
      int off = j * 8192 + tid * 16;
      int row = off >> 7, col = off & 127;
      int gc = col ^ ((row & 7) << 4);
      gload_lds16(bA + (long)row * Kb + kbyte + gc, &lds[bb][row * 128 + col]);
    }
    #pragma unroll
    for (int j = 0; j < 2; ++j) {
      int off = j * 8192 + tid * 16;
      int row = off >> 7, col = off & 127;
      int gc = col ^ ((row & 7) << 4);
      gload_lds16(bB + (long)row * Kb + kbyte + gc, &lds[bb][16384 + row * 128 + col]);
    }
  };
  auto readA = [&](int c, int g, int kk) -> bf16x8 {
    int row = wm * 64 + g * 16 + lr;
    int colb = kk * 64 + kh * 16;
    return *(const bf16x8*)&lds[c][row * 128 + (colb ^ ((row & 7) << 4))];
  };
  auto readB = [&](int c, int ni, int kk) -> bf16x8 {
    int row = wn * 32 + ni * 16 + lr;
    int colb = kk * 64 + kh * 16;
    return *(const bf16x8*)&lds[c][16384 + row * 128 + (colb ^ ((row & 7) << 4))];
  };

  const int nt = K >> 6;
  stage(0, 0);
  asm volatile("s_waitcnt vmcnt(0)" ::: "memory");
  BAR;

  for (int t = 0; t < nt; ++t) {
    const int c = t & 1, cn = c ^ 1;
    if (t + 1 < nt) stage(cn, t + 1);
    bf16x8 af[4], bfr[2];
    #pragma unroll
    for (int kk = 0; kk < 2; ++kk) {
      #pragma unroll
      for (int i = 0; i < 4; ++i) af[i] = readA(c, i, kk);
      #pragma unroll
      for (int i = 0; i < 2; ++i) bfr[i] = readB(c, i, kk);
      __builtin_amdgcn_s_setprio(1);
      #pragma unroll
      for (int mi = 0; mi < 4; ++mi)
        #pragma unroll
        for (int ni = 0; ni < 2; ++ni)
          acc[mi][ni] = __builtin_amdgcn_mfma_f32_16x16x32_bf16(af[mi], bfr[ni], acc[mi][ni], 0, 0, 0);
      __builtin_amdgcn_s_setprio(0);
    }
    asm volatile("s_waitcnt vmcnt(0)" ::: "memory");
    BAR;
  }

  #pragma unroll
  for (int mi = 0; mi < 4; ++mi) {
    #pragma unroll
    for (int ni = 0; ni < 2; ++ni) {
      int n = n0 + wn * 32 + ni * 16 + lr;
      if (n >= Nstore) continue;
      float badd = 0.f;
      if (EPI == 0) { if (bias1) badd = bias1[n]; }
      if (EPI == 1) badd = (n >= 1024) ? bias2[n - 1024] : bias1[n];
      #pragma unroll
      for (int r4 = 0; r4 < 4; ++r4) {
        int m = m0 + wm * 64 + mi * 16 + kh * 4 + r4;
        if (m >= Mstore) continue;
        float v = acc[mi][ni][r4] + badd;
        if (OBF16) ((__hip_bfloat16*)Cv)[(long)m * ldc + n] = __float2bfloat16(v);
        else       ((float*)Cv)[(long)m * ldc + n] = v;
      }
    }
  }
}

// ---------- pack split3 ----------
template<bool APAT>
__global__ __launch_bounds__(256) void k_packsplit3(const float* __restrict__ s1, long stride1,
                                                    const float* __restrict__ s2, int split,
                                                    __hip_bfloat16* __restrict__ dst) {
  long idx4 = ((long)blockIdx.x * 256 + threadIdx.x) * 4;
  int rrow = (int)(idx4 >> 10), c = (int)(idx4 & 1023);
  const float* src = (rrow < split) ? s1 + (long)rrow * stride1 + c
                                    : s2 + (long)(rrow - split) * 1024 + c;
  float4 v = *(const float4*)src;
  float f[4] = {v.x, v.y, v.z, v.w};
  unsigned short h[4], l4[4];
  #pragma unroll
  for (int i = 0; i < 4; ++i) {
    h[i] = f2bf(f[i]);
    l4[i] = f2bf(f[i] - bf2f(h[i]));
  }
  unsigned short* d = (unsigned short*)dst + (long)rrow * 3072;
  ushort4 hv = {h[0], h[1], h[2], h[3]};
  ushort4 lv = {l4[0], l4[1], l4[2], l4[3]};
  *(ushort4*)(d + c)        = hv;
  *(ushort4*)(d + 1024 + c) = APAT ? hv : lv;
  *(ushort4*)(d + 2048 + c) = APAT ? lv : hv;
}

// ---------- dual f32 -> bf16 vector cast ----------
__global__ __launch_bounds__(256) void k_cast4d(const float* __restrict__ x0,
                                                __hip_bfloat16* __restrict__ y0,
                                                const float* __restrict__ x1,
                                                __hip_bfloat16* __restrict__ y1, long n4) {
  long i = (long)blockIdx.x * 256 + threadIdx.x;
  if (i >= n4) return;
  const float* x = blockIdx.y ? x1 : x0;
  __hip_bfloat16* y = blockIdx.y ? y1 : y0;
  float4 v = ((const float4*)x)[i];
  ushort4 o = {f2bf(v.x), f2bf(v.y), f2bf(v.z), f2bf(v.w)};
  ((ushort4*)y)[i] = o;
}

// ---------- pack Bbig[cat][n(2048)][k(2048)] ----------
__global__ __launch_bounds__(256) void k_packBbig(const float* __restrict__ Ws2s,
                                                  const float* __restrict__ We2e,
                                                  const float* __restrict__ Ws2e,
                                                  const float* __restrict__ We2s,
                                                  __hip_bfloat16* __restrict__ dst) {
  long idx4 = ((long)blockIdx.x * 256 + threadIdx.x) * 4;
  long rowid = idx4 >> 11;
  int c = (int)(idx4 & 2047);
  int cat = (int)(rowid >> 11);
  int n = (int)(rowid & 2047);
  const float* src;
  if (n < 1024) src = (c < 1024) ? Ws2s + ((long)cat * 1024 + n) * 1024 + c
                                 : Ws2e + ((long)cat * 1024 + n) * 1024 + (c - 1024);
  else          src = (c < 1024) ? We2s + ((long)cat * 1024 + (n - 1024)) * 1024 + c
                                 : We2e + ((long)cat * 1024 + (n - 1024)) * 1024 + (c - 1024);
  float4 v = *(const float4*)src;
  ushort4 o = {f2bf(v.x), f2bf(v.y), f2bf(v.z), f2bf(v.w)};
  *(ushort4*)((unsigned short*)dst + idx4) = o;
}

// ---------- fused GELU+LN+rowdot both halves; s-half split3-packs ----------
__global__ __launch_bounds__(512) void k_ln_se(float* __restrict__ se,
                                               const float* __restrict__ sg, const float* __restrict__ sbe,
                                               const float* __restrict__ eg, const float* __restrict__ ebe,
                                               const float* __restrict__ msw, const float* __restrict__ msb,
                                               const float* __restrict__ mew, const float* __restrict__ meb,
                                               float* __restrict__ smv, float* __restrict__ emv,
                                               __hip_bfloat16* __restrict__ ssp) {
  int r = blockIdx.x;
  int tid = threadIdx.x;
  int half = tid >> 8;
  int c4 = tid & 255;
  int w8 = tid >> 6;
  const float* g    = half ? eg : sg;
  const float* beta = half ? ebe : sbe;
  const float* wv   = half ? mew : msw;
  float4* rowp = (float4*)(se + (long)r * 2048 + half * 1024);
  float4 x = rowp[c4];
  float v[4] = {gelu_exact(x.x), gelu_exact(x.y), gelu_exact(x.z), gelu_exact(x.w)};
  float s = v[0] + v[1] + v[2] + v[3];
  float s2 = v[0]*v[0] + v[1]*v[1] + v[2]*v[2] + v[3]*v[3];
  __shared__ float red0[8], red1[8];
  for (int off = 32; off; off >>= 1) { s += __shfl_xor(s, off); s2 += __shfl_xor(s2, off); }
  if ((tid & 63) == 0) { red0[w8] = s; red1[w8] = s2; }
  __syncthreads();
  s  = red0[half*4] + red0[half*4+1] + red0[half*4+2] + red0[half*4+3];
  s2 = red1[half*4] + red1[half*4+1] + red1[half*4+2] + red1[half*4+3];
  float mu  = s / 1024.0f;
  float var = s2 / 1024.0f - mu * mu;
  float inv = 1.0f / sqrtf(var + 1e-5f);
  float4 gg = ((const float4*)g)[c4], bb = ((const float4*)beta)[c4];
  float y[4] = {(v[0]-mu)*inv*gg.x + bb.x, (v[1]-mu)*inv*gg.y + bb.y,
                (v[2]-mu)*inv*gg.z + bb.z, (v[3]-mu)*inv*gg.w + bb.w};
  float4 w4 = ((const float4*)wv)[c4];
  float d = y[0]*w4.x + y[1]*w4.y + y[2]*w4.z + y[3]*w4.w;
  for (int off = 32; off; off >>= 1) d += __shfl_xor(d, off);
  __syncthreads();
  if ((tid & 63) == 0) red0[w8] = d;
  __syncthreads();
  if ((tid & 255) == 0) {
    float dv = red0[half*4] + red0[half*4+1] + red0[half*4+2] + red0[half*4+3];
    if (half == 0) smv[r] = dv + msb[0];
    else           emv[r] = dv + meb[0];
  }
  if (half == 0) {
    unsigned short h[4], l4[4];
    #pragma unroll
    for (int i = 0; i < 4; ++i) { h[i] = f2bf(y[i]); l4[i] = f2bf(y[i] - bf2f(h[i])); }
    ushort4 hv = {h[0], h[1], h[2], h[3]};
    ushort4 lv = {l4[0], l4[1], l4[2], l4[3]};
    unsigned short* dst = (unsigned short*)ssp + (long)r * 3072 + c4 * 4;
    *(ushort4*)dst          = hv;
    *(ushort4*)(dst + 1024) = hv;
    *(ushort4*)(dst + 2048) = lv;
  } else {
    float4 yo = {y[0], y[1], y[2], y[3]};
    rowp[c4] = yo;
  }
}

// ---------- GELU+LN over 7168 (bf16 in) -> a_cat halves; grid 3584 ----------
__global__ __launch_bounds__(256) void k_gelu_ln_cats(const __hip_bfloat16* __restrict__ h,
                                                      const float* __restrict__ sg,
                                                      const float* __restrict__ sbe,
                                                      const float* __restrict__ eg,
                                                      const float* __restrict__ ebe,
                                                      __hip_bfloat16* __restrict__ a_cat) {
  int r = blockIdx.x;
  int half = (r >= 2 * KP) ? 1 : 0;
  int r2 = r - half * 2 * KP;
  int b = (r2 >= KP) ? 1 : 0, k = r2 - KP * b;
  const float* g    = half ? eg : sg;
  const float* beta = half ? ebe : sbe;
  const ushort4* row = (const ushort4*)((const unsigned short*)h + (long)r * 7168);
  float v[28];
  float s = 0.f, s2 = 0.f;
  #pragma unroll
  for (int j = 0; j < 7; ++j) {
    ushort4 u = row[threadIdx.x + 256 * j];
    #pragma unroll
    for (int e = 0; e < 4; ++e) {
      float x = bf2f(((const unsigned short*)&u)[e]);
      float ge = gelu_exact(x);
      v[j * 4 + e] = ge; s += ge; s2 += ge * ge;
    }
  }
  __shared__ float red0[4], red1[4];
  for (int off = 32; off; off >>= 1) { s += __shfl_xor(s, off); s2 += __shfl_xor(s2, off); }
  int w = threadIdx.x >> 6;
  if ((threadIdx.x & 63) == 0) { red0[w] = s; red1[w] = s2; }
  __syncthreads();
  s  = red0[0] + red0[1] + red0[2] + red0[3];
  s2 = red1[0] + red1[1] + red1[2] + red1[3];
  float mu  = s / 7168.0f;
  float var = s2 / 7168.0f - mu * mu;
  float inv = 1.0f / sqrtf(var + 1e-5f);
  #pragma unroll
  for (int j = 0; j < 7; ++j) {
    int c0 = (threadIdx.x + 256 * j) * 4;
    int n = c0 >> 10, f = c0 & 1023;
    unsigned short o[4];
    #pragma unroll
    for (int e = 0; e < 4; ++e)
      o[e] = f2bf((v[j * 4 + e] - mu) * inv * g[c0 + e] + beta[c0 + e]);
    ushort4 ov = {o[0], o[1], o[2], o[3]};
    *(ushort4*)((unsigned short*)a_cat + ((long)((b * NC_ + n) * NK + k)) * 2048 + half * 1024 + f) = ov;
  }
}

// ---------- banded scores ----------
__global__ __launch_bounds__(512) void k_band(const float* __restrict__ s2m,
                                              const float* __restrict__ se,
                                              const float* __restrict__ smv,
                                              const float* __restrict__ emv,
                                              float* __restrict__ band) {
  __shared__ float ebuf[2][1024];
  int blk = blockIdx.x;
  int b = blk >> 8;
  int s0 = (blk & 255) * 8;
  int w = threadIdx.x >> 6, l = threadIdx.x & 63;
  int s = s0 + w;
  int tid = threadIdx.x;
  float sreg[16];
  const float* sp = s2m + ((long)(b << 11) + s) * 1024;
  #pragma unroll
  for (int qq = 0; qq < 16; ++qq) sreg[qq] = sp[l + 64 * qq];
  float myS = smv[(b << 11) + s];
  if (l < 32) {
    int j = l;
    if (j >= 30 || s + j >= S_)
      band[((long)(b << 11) + s) * 32 + j] = -3.0e38f;
  }
  {
    const float* ep = se + ((long)(b << 11) + s0) * 2048 + 1024;
    ebuf[0][tid * 2]     = ep[tid * 2];
    ebuf[0][tid * 2 + 1] = ep[tid * 2 + 1];
  }
  for (int it = 0; it < 37; ++it) {
    int t = s0 + it;
    __syncthreads();
    if (it + 1 < 37 && s0 + it + 1 < S_) {
      const float* ep = se + ((long)(b << 11) + s0 + it + 1) * 2048 + 1024;
      ebuf[(it + 1) & 1][tid * 2]     = ep[tid * 2];
      ebuf[(it + 1) & 1][tid * 2 + 1] = ep[tid * 2 + 1];
    }
    int j = t - s;
    if (t < S_ && j >= 0 && j < 30) {
      const float* eb = ebuf[it & 1];
      float acc = 0.f;
      #pragma unroll
      for (int qq = 0; qq < 16; ++qq) acc += sreg[qq] * eb[l + 64 * qq];
      for (int off = 32; off; off >>= 1) acc += __shfl_xor(acc, off);
      if (l == 0)
        band[((long)(b << 11) + s) * 32 + j] = acc + myS + emv[(b << 11) + t];
    }
  }
}

// ================= parallel exact top-k =================
__global__ __launch_bounds__(1024) void k_tkhist(const float* __restrict__ band,
                                                 unsigned* __restrict__ ghist) {
  int b = blockIdx.y;
  const float* bb = band + (long)b * 65536;
  __shared__ unsigned lh[4096];
  int tid = threadIdx.x;
  #pragma unroll
  for (int j = 0; j < 4; ++j) lh[tid + j * 1024] = 0;
  __syncthreads();
  int base = blockIdx.x * 4096;
  #pragma unroll
  for (int j = 0; j < 4; ++j) {
    unsigned key = fkey(bb[base + tid + j * 1024]);
    atomicAdd(&lh[key >> 20], 1u);
  }
  __syncthreads();
  #pragma unroll
  for (int j = 0; j < 4; ++j) {
    unsigned v = lh[tid + j * 1024];
    if (v) atomicAdd(&ghist[b * 4096 + tid + j * 1024], v);
  }
}

__global__ __launch_bounds__(1024) void k_tkscan(const unsigned* __restrict__ ghist,
                                                 const int* __restrict__ masks,
                                                 unsigned* __restrict__ sel) {
  int b = blockIdx.x;
  int tid = threadIdx.x;
  __shared__ unsigned cs[1024];
  __shared__ int red[16];
  __shared__ int sh_kv;
  int pm = masks[b * S_ + tid] + masks[b * S_ + 1024 + tid];
  for (int off = 32; off; off >>= 1) pm += __shfl_xor(pm, off);
  if ((tid & 63) == 0) red[tid >> 6] = pm;
  __syncthreads();
  if (tid == 0) {
    int msum = 0;
    for (int i = 0; i < 16; ++i) msum += red[i];
    int kv = (int)((float)msum * 0.4f);
    if (kv > MAXK) kv = MAXK;
    sh_kv = kv;
  }
  __syncthreads();
  int kv = sh_kv;
  unsigned hbin[4];
  unsigned ssum = 0;
  #pragma unroll
  for (int j = 0; j < 4; ++j) { hbin[j] = ghist[b * 4096 + tid * 4 + j]; ssum += hbin[j]; }
  cs[tid] = ssum;
  __syncthreads();
  for (int off = 1; off < 1024; off <<= 1) {
    unsigned add = (tid + off < 1024) ? cs[tid + off] : 0u;
    __syncthreads();
    cs[tid] += add;
    __syncthreads();
  }
  unsigned above = cs[tid] - ssum;
  if (kv > 0) {
    unsigned aa = above;
    for (int j = 3; j >= 0; --j) {
      if (aa < (unsigned)kv && aa + hbin[j] >= (unsigned)kv) sel[b * 2] = (unsigned)(tid * 4 + j);
      aa += hbin[j];
    }
  }
  if (tid == 0) {
    sel[b * 2 + 1] = (unsigned)kv;
    if (kv == 0) sel[b * 2] = 0xFFFFFFFFu;
  }
}

__global__ __launch_bounds__(1024) void k_tkcollect(const float* __restrict__ band,
                                                    const unsigned* __restrict__ sel,
                                                    unsigned* __restrict__ cand,
                                                    unsigned* __restrict__ gcnt) {
  int b = blockIdx.y;
  const float* bb = band + (long)b * 65536;
  unsigned thr = sel[b * 2];
  int base = blockIdx.x * 4096;
  int tid = threadIdx.x;
  #pragma unroll
  for (int j = 0; j < 4; ++j) {
    int i = base + tid + j * 1024;
    unsigned key = fkey(bb[i]);
    if ((key >> 20) >= thr) {
      unsigned p = atomicAdd(&gcnt[b], 1u);
      cand[(long)b * 65536 + p] = (unsigned)i;
    }
  }
}

__device__ __forceinline__ void bitonic1024(unsigned* buf) {
  int tid = threadIdx.x;
  __syncthreads();
  for (int k = 2; k <= 1024; k <<= 1)
    for (int j = k >> 1; j > 0; j >>= 1) {
      int ixj = tid ^ j;
      if (ixj > tid) {
        unsigned a = buf[tid], c = buf[ixj];
        bool up = ((tid & k) == 0);
        if (up ? (a > c) : (a < c)) { buf[tid] = c; buf[ixj] = a; }
      }
      __syncthreads();
    }
}

__global__ __launch_bounds__(1024) void k_tkfinal(const float* __restrict__ band,
                                                  const unsigned* __restrict__ cand,
                                                  const unsigned* __restrict__ gcnt,
                                                  const unsigned* __restrict__ sel,
                                                  int* __restrict__ starts, int* __restrict__ ends,
                                                  float* __restrict__ tk, int* __restrict__ kvalid_out) {
  int b = blockIdx.x;
  const float* bb = band + (long)b * 65536;
  const unsigned* cd = cand + (long)b * 65536;
  int nC = (int)gcnt[b];
  int kv = (int)sel[b * 2 + 1];
  __shared__ unsigned hist[256];
  __shared__ int sh_digit, sh_R;
  __shared__ unsigned cntG, cntE;
  __shared__ unsigned listG[832];
  __shared__ unsigned listE[1024];
  __shared__ unsigned buf[1024];
  int tid = threadIdx.x;

  unsigned prefix = 0;
  int R = kv;
  if (kv > 0) {
    for (int shift = 24; shift >= 0; shift -= 8) {
      if (tid < 256) hist[tid] = 0;
      __syncthreads();
      for (int j = tid; j < nC; j += 1024) {
        unsigned key = fkey(bb[cd[j]]);
        bool ok = (shift == 24) || ((key >> (shift + 8)) == (prefix >> (shift + 8)));
        if (ok) atomicAdd(&hist[(key >> shift) & 255u], 1u);
      }
      __syncthreads();
      if (tid == 0) {
        unsigned cum = 0; int d;
        for (d = 255; d >= 0; --d) {
          unsigned hc = hist[d];
          if (cum + hc >= (unsigned)R) break;
          cum += hc;
        }
        if (d < 0) d = 0;
        sh_digit = d; sh_R = R - (int)cum;
      }
      __syncthreads();
      prefix |= ((unsigned)sh_digit) << shift;
      R = sh_R;
      __syncthreads();
    }
  }
  if (tid == 0) { cntG = 0; cntE = 0; }
  __syncthreads();
  if (kv > 0) {
    for (int j = tid; j < nC; j += 1024) {
      unsigned i = cd[j];
      unsigned key = fkey(bb[i]);
      if (key > prefix) { unsigned p = atomicAdd(&cntG, 1u); if (p < 832) listG[p] = i; }
      else if (key == prefix) { unsigned p = atomicAdd(&cntE, 1u); if (p < 1024) listE[p] = i; }
    }
  }
  __syncthreads();
  int nG = (int)cntG, nE = (int)cntE, need = R;
  buf[tid] = (tid < nE) ? listE[tid] : 0xFFFFFFFFu;
  bitonic1024(buf);
  if (tid < need) listG[nG + tid] = buf[tid];
  __syncthreads();
  unsigned v2 = (tid < (unsigned)kv) ? listG[tid] : 0xFFFFFFFFu;
  __syncthreads();
  buf[tid] = v2;
  bitonic1024(buf);
  {
    int s, t; float val;
    if (tid < kv) {
      unsigned i = buf[tid];
      s = (int)(i >> 5); t = s + (int)(i & 31);
      val = bb[i];
    } else {
      s = S_ - 1; t = S_ - 1;
      val = bb[(S_ - 1) * 32 + 0];
    }
    starts[b * NK + tid] = s;
    ends[b * NK + tid] = t;
    tk[b * NK + tid] = val;
  }
  if (tid == 0) kvalid_out[b] = kv;
}

// ---------- gather span reps to bf16 ----------
__global__ __launch_bounds__(256) void k_gather(const float* __restrict__ emb,
                                                const int* __restrict__ starts,
                                                const int* __restrict__ ends,
                                                __hip_bfloat16* __restrict__ reps_s,
                                                __hip_bfloat16* __restrict__ reps_e) {
  int r = blockIdx.x;
  int b = (r >= KP) ? 1 : 0, k = r - KP * b;
  long ob = (long)r * 1024;
  const float4* ps = (const float4*)(emb + ((long)b * S_ + starts[b * NK + k]) * 1024);
  const float4* pe = (const float4*)(emb + ((long)b * S_ + ends[b * NK + k]) * 1024);
  unsigned short* ds = (unsigned short*)reps_s + ob;
  unsigned short* de = (unsigned short*)reps_e + ob;
  int c4 = threadIdx.x;
  float4 a = ps[c4], e = pe[c4];
  ushort4 oa = {f2bf(a.x), f2bf(a.y), f2bf(a.z), f2bf(a.w)};
  ushort4 oe = {f2bf(e.x), f2bf(e.y), f2bf(e.z), f2bf(e.w)};
  *(ushort4*)(ds + c4 * 4) = oa;
  *(ushort4*)(de + c4 * 4) = oe;
}

// ---------- antecedent bias vector ----------
__global__ __launch_bounds__(256) void k_bias(const __hip_bfloat16* __restrict__ a_cat,
                                              const float* __restrict__ Bs2s, const float* __restrict__ Be2e,
                                              const float* __restrict__ Bs2e, const float* __restrict__ Be2s,
                                              float* __restrict__ biasv) {
  int w = threadIdx.x >> 6, l = threadIdx.x & 63;
  int rid = blockIdx.x * 4 + w;
  if (rid >= Z_ * KP) return;
  int z = rid / KP, li = rid - z * KP;
  int cat = z % NC_;
  const unsigned short* ar = (const unsigned short*)a_cat + ((long)z * NK + li) * 2048;
  const float* b1 = Bs2s + cat * 1024;
  const float* b2 = Be2s + cat * 1024;
  const float* b3 = Be2e + cat * 1024;
  const float* b4 = Bs2e + cat * 1024;
  float acc = 0.f;
  for (int qq = 0; qq < 16; ++qq) {
    int c = l + 64 * qq;
    acc += bf2f(ar[c]) * (b1[c] + b2[c]);
    acc += bf2f(ar[1024 + c]) * (b3[c] + b4[c]);
  }
  for (int off = 32; off; off >>= 1) acc += __shfl_xor(acc, off);
  if (l == 0) biasv[z * NK + li] = acc;
}

// =====================================================================
extern "C" void kernel_launch(void* const* d_in, const int* in_sizes, int n_in,
                              void* d_out, int out_size, void* d_ws, size_t ws_size,
                              hipStream_t stream) {
  const float* x_emb = (const float*)d_in[0];
  const int*   masks = (const int*)d_in[1];
  const float* smW  = (const float*)d_in[2];
  const float* smb  = (const float*)d_in[3];
  const float* smg  = (const float*)d_in[4];
  const float* smbe = (const float*)d_in[5];
  const float* emW  = (const float*)d_in[6];
  const float* embb = (const float*)d_in[7];
  const float* emg  = (const float*)d_in[8];
  const float* embe = (const float*)d_in[9];
  const float* msw  = (const float*)d_in[10];
  const float* msb  = (const float*)d_in[11];
  const float* mew  = (const float*)d_in[12];
  const float* meb  = (const float*)d_in[13];
  const float* s2eW = (const float*)d_in[14];
  const float* s2eb = (const float*)d_in[15];
  const float* csW  = (const float*)d_in[16];
  const float* csb  = (const float*)d_in[17];
  const float* csg  = (const float*)d_in[18];
  const float* csbe = (const float*)d_in[19];
  const float* ceW  = (const float*)d_in[20];
  const float* ceb  = (const float*)d_in[21];
  const float* ceg  = (const float*)d_in[22];
  const float* cebe = (const float*)d_in[23];
  const float* Ws2s = (const float*)d_in[24];
  const float* We2e = (const float*)d_in[25];
  const float* Ws2e = (const float*)d_in[26];
  const float* We2s = (const float*)d_in[27];
  const float* Bs2s = (const float*)d_in[28];
  const float* Be2e = (const float*)d_in[29];
  const float* Bs2e = (const float*)d_in[30];
  const float* Be2s = (const float*)d_in[31];
  float* outp = (float*)d_out;
  char* ws = (char*)d_ws;
  (void)in_sizes; (void)n_in; (void)out_size; (void)ws_size;

  const size_t o_embsp = 0;
  const size_t o_bse   = 25165824;
  const size_t o_ssp   = 0;
  const size_t o_s2W   = 25165824;
  const size_t o_repss = 0;
  const size_t o_repse = 4194304;
  const size_t o_csWb  = 8388608;
  const size_t o_ceWb  = 23068672;   // = o_csWb + 7168*1024*2 bytes (contiguous after csWb)
  const size_t o_Bbig  = 0;
  const size_t o_se    = 37748736;
  const size_t o_s2    = 71303168;
  const size_t o_h     = 88080384;   // h_all bf16 [3584][7168] ; later Vcat bf16 [14][1024][2048]
  const size_t o_acat  = 146800640;
  const size_t o_smv   = 205520896;
  const size_t o_emv   = o_smv + 16384;
  const size_t o_band  = o_emv + 16384;
  const size_t o_starts= o_band + 524288;
  const size_t o_ends  = o_starts + 8192;
  const size_t o_tk    = o_ends + 8192;
  const size_t o_kv    = o_tk + 8192;
  const size_t o_biasv = o_kv + 256;
  const size_t o_ghist = o_biasv + 61440;
  const size_t o_gcnt  = o_ghist + 32768;
  const size_t o_sel   = o_gcnt + 256;
  const size_t o_cand  = o_sel + 256;

  __hip_bfloat16* embsp = (__hip_bfloat16*)(ws + o_embsp);
  __hip_bfloat16* bse   = (__hip_bfloat16*)(ws + o_bse);
  __hip_bfloat16* ssp   = (__hip_bfloat16*)(ws + o_ssp);
  __hip_bfloat16* s2Wsp = (__hip_bfloat16*)(ws + o_s2W);
  __hip_bfloat16* repss = (__hip_bfloat16*)(ws + o_repss);
  __hip_bfloat16* repse = (__hip_bfloat16*)(ws + o_repse);
  __hip_bfloat16* csWb  = (__hip_bfloat16*)(ws + o_csWb);
  __hip_bfloat16* ceWb  = (__hip_bfloat16*)(ws + o_ceWb);
  __hip_bfloat16* Bbig  = (__hip_bfloat16*)(ws + o_Bbig);
  float* se_buf = (float*)(ws + o_se);
  float* s2_buf = (float*)(ws + o_s2);
  __hip_bfloat16* h_all = (__hip_bfloat16*)(ws + o_h);
  __hip_bfloat16* Vcat  = (__hip_bfloat16*)(ws + o_h);
  __hip_bfloat16* a_cat = (__hip_bfloat16*)(ws + o_acat);
  float* smv_p = (float*)(ws + o_smv);
  float* emv_p = (float*)(ws + o_emv);
  float* band_p = (float*)(ws + o_band);
  int* starts_p = (int*)(ws + o_starts);
  int* ends_p = (int*)(ws + o_ends);
  float* tk_p = (float*)(ws + o_tk);
  int* kv_p = (int*)(ws + o_kv);
  float* biasv_p = (float*)(ws + o_biasv);
  unsigned* ghist_p = (unsigned*)(ws + o_ghist);
  unsigned* gcnt_p = (unsigned*)(ws + o_gcnt);
  unsigned* sel_p = (unsigned*)(ws + o_sel);
  unsigned* cand_p = (unsigned*)(ws + o_cand);

  // ---- stage A ----
  k_packsplit3<true ><<<4096, 256, 0, stream>>>(x_emb, 1024, x_emb, 4096, embsp);
  k_packsplit3<false><<<2048, 256, 0, stream>>>(smW, 1024, emW, 1024, bse);
  k_gemm2b<false, 1><<<512, 512, 0, stream>>>(embsp, bse,
      se_buf, smb, embb, 3072, 16, 2048, 4096, 2048);
  k_ln_se<<<4096, 512, 0, stream>>>(se_buf, smg, smbe, emg, embe, msw, msb, mew, meb,
                                    smv_p, emv_p, ssp);

  // ---- stage C ----
  k_packsplit3<false><<<1024, 256, 0, stream>>>(s2eW, 1024, s2eW, 1024, s2Wsp);
  k_gemm2b<false, 0><<<256, 512, 0, stream>>>(ssp, s2Wsp,
      s2_buf, s2eb, nullptr, 3072, 8, 1024, 4096, 1024);
  k_band<<<512, 512, 0, stream>>>(s2_buf, se_buf, smv_p, emv_p, band_p);

  // ---- stage D: parallel exact top-k ----
  hipMemsetAsync(ws + o_ghist, 0, 33024, stream);   // ghist + gcnt
  k_tkhist<<<dim3(16, 2), 1024, 0, stream>>>(band_p, ghist_p);
  k_tkscan<<<2, 1024, 0, stream>>>(ghist_p, masks, sel_p);
  k_tkcollect<<<dim3(16, 2), 1024, 0, stream>>>(band_p, sel_p, cand_p, gcnt_p);
  k_tkfinal<<<2, 1024, 0, stream>>>(band_p, cand_p, gcnt_p, sel_p,
                                    starts_p, ends_p, tk_p, kv_p);

  // ---- stage E/F: gather + merged FC on deep kernel (M = 3584 block-diag) ----
  k_gather<<<2 * KP, 256, 0, stream>>>(x_emb, starts_p, ends_p, repss, repse);
  k_cast4d<<<dim3(7168, 2), 256, 0, stream>>>(csW, csWb, ceW, ceWb, 1835008);
  k_gemm8<true, 0, true><<<dim3(392, 1, 1), 512, 0, stream>>>(repss, repse, csWb,
      h_all, csb, ceb, nullptr, nullptr, 1024, 28, 0, (long)7168 * 1024, 0, 0,
      7168, 3584, 7168, 2 * KP);
  k_packBbig<<<28672, 256, 0, stream>>>(Ws2s, We2e, Ws2e, We2s, Bbig);
  k_gelu_ln_cats<<<3584, 256, 0, stream>>>(h_all, csg, csbe, ceg, cebe, a_cat);

  // ---- stage G: Vcat, bias, logits (reg-pipelined deep kernel) ----
  k_gemm8<true, 0, false><<<dim3(32, 1, Z_), 512, 0, stream>>>(a_cat, nullptr, Bbig,
      Vcat, nullptr, nullptr, nullptr, nullptr, 2048, 8, (long)NK * 2048,
      (long)2048 * 2048, 1, (long)NK * 2048, 2048, NK, 2048, 0);
  k_bias<<<(Z_ * KP) / 4, 256, 0, stream>>>(a_cat, Bs2s, Be2e, Bs2e, Be2s, biasv_p);
  k_gemm8<false, 2, false><<<dim3(16, 1, Z_), 512, 0, stream>>>(a_cat, nullptr, Vcat,
      outp, biasv_p, nullptr, tk_p, kv_p, 2048, 4, (long)NK * 2048,
      (long)NK * 2048, 0, (long)MAXK * MAXK, MAXK, MAXK, MAXK, 0);
}